// Round 3
// baseline (1639.404 us; speedup 1.0000x reference)
//
#include <hip/hip_runtime.h>

#define DEV __device__ __forceinline__

constexpr int Bb = 32, Tt = 64, Ff = 128, Dd = 64, Hh = 4, Kk = 32;

DEV void fma_row(float* acc, float xv, const float* wrow) {
    const float4* w4 = reinterpret_cast<const float4*>(wrow);
#pragma unroll
    for (int c = 0; c < 8; ++c) {
        float4 w = w4[c];
        acc[4*c+0] = fmaf(xv, w.x, acc[4*c+0]);
        acc[4*c+1] = fmaf(xv, w.y, acc[4*c+1]);
        acc[4*c+2] = fmaf(xv, w.z, acc[4*c+2]);
        acc[4*c+3] = fmaf(xv, w.w, acc[4*c+3]);
    }
}

// MODE 0: temporal attention (rows = T, block per (b,f)), writes fp32 partial.
// MODE 1: feature attention (rows = F, block per (b,t)), reads partial, adds, writes final.
template<int NROWS, int MODE>
__global__ __launch_bounds__(NROWS)
void axial_attn(const float* __restrict__ x,
                const float* __restrict__ wq, const float* __restrict__ bq,
                const float* __restrict__ wk, const float* __restrict__ bk,
                const float* __restrict__ wv, const float* __restrict__ bv,
                const float* __restrict__ wo, const float* __restrict__ bo,
                float* __restrict__ out)
{
    constexpr int KVP = 36;   // floats per k/v row: 144B, float4-aligned, stride breaks 32-bank harmonics
    __shared__ float k_s[NROWS * KVP];
    __shared__ float v_s[NROWS * KVP];

    const int tid = threadIdx.x;
    const int bid = blockIdx.x;
    int base, rstride;
    if (MODE == 0) { int b = bid >> 7, f = bid & 127; base = b*(Tt*Ff*Dd) + f*Dd; rstride = Ff*Dd; }
    else           { base = bid * (Ff*Dd); rstride = Dd; }

    const float scale = 0.17677669529663687f;  // 1/sqrt(32)
    const float4* xr4 = reinterpret_cast<const float4*>(x + base + tid*rstride);

    float out_acc[Dd];
#pragma unroll
    for (int d = 0; d < Dd; ++d) out_acc[d] = 0.f;

    float qa[Kk], ka[Kk];

#pragma unroll 1
    for (int h = 0; h < Hh; ++h) {
        // ---- q projection: qa[k] = sum_d x[d] * wq[d,h,k] ----
#pragma unroll
        for (int k2 = 0; k2 < Kk; ++k2) qa[k2] = 0.f;
#pragma unroll 1
        for (int p = 0; p < 16; ++p) {
            float4 xv = xr4[p];
            fma_row(qa, xv.x, wq + (4*p+0)*(Hh*Kk) + h*Kk);
            fma_row(qa, xv.y, wq + (4*p+1)*(Hh*Kk) + h*Kk);
            fma_row(qa, xv.z, wq + (4*p+2)*(Hh*Kk) + h*Kk);
            fma_row(qa, xv.w, wq + (4*p+3)*(Hh*Kk) + h*Kk);
        }
#pragma unroll
        for (int k2 = 0; k2 < Kk; ++k2)
            qa[k2] = (qa[k2] + bq[h*Kk+k2]) * scale;

        // ---- k projection -> LDS ----
#pragma unroll
        for (int k2 = 0; k2 < Kk; ++k2) ka[k2] = 0.f;
#pragma unroll 1
        for (int p = 0; p < 16; ++p) {
            float4 xv = xr4[p];
            fma_row(ka, xv.x, wk + (4*p+0)*(Hh*Kk) + h*Kk);
            fma_row(ka, xv.y, wk + (4*p+1)*(Hh*Kk) + h*Kk);
            fma_row(ka, xv.z, wk + (4*p+2)*(Hh*Kk) + h*Kk);
            fma_row(ka, xv.w, wk + (4*p+3)*(Hh*Kk) + h*Kk);
        }
        {
            float4* kp = reinterpret_cast<float4*>(&k_s[tid*KVP]);
#pragma unroll
            for (int c = 0; c < 8; ++c)
                kp[c] = make_float4(ka[4*c+0] + bk[h*Kk+4*c+0],
                                    ka[4*c+1] + bk[h*Kk+4*c+1],
                                    ka[4*c+2] + bk[h*Kk+4*c+2],
                                    ka[4*c+3] + bk[h*Kk+4*c+3]);
        }

        // ---- v projection -> LDS ----
#pragma unroll
        for (int k2 = 0; k2 < Kk; ++k2) ka[k2] = 0.f;
#pragma unroll 1
        for (int p = 0; p < 16; ++p) {
            float4 xv = xr4[p];
            fma_row(ka, xv.x, wv + (4*p+0)*(Hh*Kk) + h*Kk);
            fma_row(ka, xv.y, wv + (4*p+1)*(Hh*Kk) + h*Kk);
            fma_row(ka, xv.z, wv + (4*p+2)*(Hh*Kk) + h*Kk);
            fma_row(ka, xv.w, wv + (4*p+3)*(Hh*Kk) + h*Kk);
        }
        {
            float4* vp = reinterpret_cast<float4*>(&v_s[tid*KVP]);
#pragma unroll
            for (int c = 0; c < 8; ++c)
                vp[c] = make_float4(ka[4*c+0] + bv[h*Kk+4*c+0],
                                    ka[4*c+1] + bv[h*Kk+4*c+1],
                                    ka[4*c+2] + bv[h*Kk+4*c+2],
                                    ka[4*c+3] + bv[h*Kk+4*c+3]);
        }
        __syncthreads();   // k_s/v_s visible to all

        // ---- online-softmax attention over all key rows ----
        float m = -1.0e4f, l = 0.f, o[Kk];
#pragma unroll
        for (int k2 = 0; k2 < Kk; ++k2) o[k2] = 0.f;

#pragma unroll 1
        for (int j = 0; j < NROWS; ++j) {
            const float4* kr = reinterpret_cast<const float4*>(&k_s[j*KVP]);
            float s0=0.f, s1=0.f, s2=0.f, s3=0.f;
#pragma unroll
            for (int c = 0; c < 8; ++c) {
                float4 kw = kr[c];
                s0 = fmaf(qa[4*c+0], kw.x, s0);
                s1 = fmaf(qa[4*c+1], kw.y, s1);
                s2 = fmaf(qa[4*c+2], kw.z, s2);
                s3 = fmaf(qa[4*c+3], kw.w, s3);
            }
            float s  = (s0+s1)+(s2+s3);
            float mn = fmaxf(m, s);
            float al = __expf(m - mn);
            float pp = __expf(s - mn);
            l = l*al + pp;
            const float4* vr = reinterpret_cast<const float4*>(&v_s[j*KVP]);
#pragma unroll
            for (int c = 0; c < 8; ++c) {
                float4 vw = vr[c];
                o[4*c+0] = fmaf(o[4*c+0], al, pp*vw.x);
                o[4*c+1] = fmaf(o[4*c+1], al, pp*vw.y);
                o[4*c+2] = fmaf(o[4*c+2], al, pp*vw.z);
                o[4*c+3] = fmaf(o[4*c+3], al, pp*vw.w);
            }
            m = mn;
        }
        float rl = 1.f / l;

        // ---- output projection from global wo (broadcast, L1-resident) ----
#pragma unroll 1
        for (int k2 = 0; k2 < Kk; ++k2) {
            float ov = o[k2] * rl;
            const float4* wr = reinterpret_cast<const float4*>(wo + h*(Kk*Dd) + k2*Dd);
#pragma unroll
            for (int c = 0; c < 16; ++c) {
                float4 w = wr[c];
                out_acc[4*c+0] = fmaf(ov, w.x, out_acc[4*c+0]);
                out_acc[4*c+1] = fmaf(ov, w.y, out_acc[4*c+1]);
                out_acc[4*c+2] = fmaf(ov, w.z, out_acc[4*c+2]);
                out_acc[4*c+3] = fmaf(ov, w.w, out_acc[4*c+3]);
            }
        }
        __syncthreads();   // all k_s/v_s reads done before next head overwrites
    }

    // ---- epilogue: fp32 in, fp32 out ----
    float* orow = out + base + tid*rstride;
    if (MODE == 1) {
        const float4* pr = reinterpret_cast<const float4*>(orow);
#pragma unroll
        for (int c = 0; c < 16; ++c) {
            float4 p = pr[c];
            out_acc[4*c+0] += p.x;
            out_acc[4*c+1] += p.y;
            out_acc[4*c+2] += p.z;
            out_acc[4*c+3] += p.w;
        }
    }
#pragma unroll
    for (int d = 0; d < Dd; ++d) out_acc[d] += bo[d];

    float4* ow = reinterpret_cast<float4*>(orow);
#pragma unroll
    for (int c = 0; c < 16; ++c)
        ow[c] = make_float4(out_acc[4*c+0], out_acc[4*c+1],
                            out_acc[4*c+2], out_acc[4*c+3]);
}

extern "C" void kernel_launch(void* const* d_in, const int* in_sizes, int n_in,
                              void* d_out, int out_size, void* d_ws, size_t ws_size,
                              hipStream_t stream) {
    const float* x   = (const float*)d_in[0];
    const float* tqw = (const float*)d_in[1];  const float* tqb = (const float*)d_in[2];
    const float* tkw = (const float*)d_in[3];  const float* tkb = (const float*)d_in[4];
    const float* tvw = (const float*)d_in[5];  const float* tvb = (const float*)d_in[6];
    const float* fqw = (const float*)d_in[7];  const float* fqb = (const float*)d_in[8];
    const float* fkw = (const float*)d_in[9];  const float* fkb = (const float*)d_in[10];
    const float* fvw = (const float*)d_in[11]; const float* fvb = (const float*)d_in[12];
    const float* tow = (const float*)d_in[13]; const float* tob = (const float*)d_in[14];
    const float* fow = (const float*)d_in[15]; const float* fob = (const float*)d_in[16];
    float* out = (float*)d_out;

    // temporal: block per (b,f), writes full fp32 partial
    hipLaunchKernelGGL((axial_attn<64,0>), dim3(Bb*Ff), dim3(64), 0, stream,
                       x, tqw, tqb, tkw, tkb, tvw, tvb, tow, tob, out);
    // feature: block per (b,t), reads partial, adds, writes final
    hipLaunchKernelGGL((axial_attn<128,1>), dim3(Bb*Tt), dim3(128), 0, stream,
                       x, fqw, fqb, fkw, fkb, fvw, fvb, fow, fob, out);
}

// Round 4
// 489.104 us; speedup vs baseline: 3.3519x; 3.3519x over previous
//
#include <hip/hip_runtime.h>

typedef unsigned short u16;
typedef unsigned int   u32;
typedef short v8s __attribute__((ext_vector_type(8)));   // 8 bf16 (A/B frag, 4 VGPR)
typedef float v4f __attribute__((ext_vector_type(4)));   // 4 fp32 (C/D frag)

#define DEV __device__ __forceinline__
#define MFMA(a,b,c) __builtin_amdgcn_mfma_f32_16x16x32_bf16((a),(b),(c),0,0,0)

constexpr int Bb = 32, Tt = 64, Ff = 128, Dd = 64, Hh = 4, Kk = 32;

DEV u16 f2b(float f) {
    u32 u = __float_as_uint(f);
    return (u16)((u + 0x7fffu + ((u >> 16) & 1u)) >> 16);   // RNE
}

// Layout rules (HW-verified fragment mappings, learn_hip m89/m120):
//   A-frag: lane holds A[m][k], m = lane&15, k = quad*8+j   -> container row-major [m][k]
//   B-frag: lane holds B[k][n], n = lane&15, k = quad*8+j   -> container [n][k]
//   C/D:    lane holds D[row][col], col = lane&15, row = quad*4+r
// MODE 0: temporal (NR=64 rows=T, block per (b,f)), writes fp32 partial.
// MODE 1: feature (NR=128 rows=F, block per (b,t)), read-add-write final.
template<int NR, int MODE>
__global__ __launch_bounds__(NR*4)
void axial_mfma(const float* __restrict__ x,
                const float* __restrict__ wq, const float* __restrict__ bq,
                const float* __restrict__ wk, const float* __restrict__ bk,
                const float* __restrict__ wv, const float* __restrict__ bv,
                const float* __restrict__ wo, const float* __restrict__ bo,
                float* __restrict__ out)
{
    constexpr int W   = NR / 16;     // waves per block (one 16-row M-tile each)
    constexpr int NT  = W * 64;
    constexpr int NRp = NR + 8;      // padded pitch (keeps 16B align: NRp*2 % 16 == 0)
    // u16 offsets into the shared arena
    constexpr int o_wlt = 0;                  // W^T   [32 ch][72 d]   (B-container for projections)
    constexpr int o_ql  = o_wlt + 32 * 72;    // Q     [NR][32]        (A-container for S)
    constexpr int o_kl  = o_ql  + NR * 32;    // K     [NR][32]        (B-container for S: [n=krow][k=ch])
    constexpr int o_vt  = o_kl  + NR * 32;    // V^T   [32 ch][NRp]    (B-container for PV: [n=ch][k=krow])
    constexpr int o_pl  = o_vt  + 32 * NRp;   // P     [NR][NRp]       (A-container for PV)
    constexpr int o_ot  = o_pl  + NR * NRp;   // O     [NR][32]        (A-container for out-proj)
    constexpr int o_wot = o_ot  + NR * 32;    // Wo^T  [64 d][40 k]    (B-container for out-proj)
    constexpr int SMEM  = o_wot + 64 * 40;
    __shared__ alignas(16) u16 sm[SMEM];

    const int tid  = threadIdx.x;
    const int w    = tid >> 6;
    const int lane = tid & 63;
    const int quad = lane >> 4;
    const int l15  = lane & 15;
    const int bid  = blockIdx.x;

    int base, rstride;
    if (MODE == 0) { int b = bid >> 7, f = bid & 127; base = b*(Tt*Ff*Dd) + f*Dd; rstride = Ff*Dd; }
    else           { base = bid * (Ff*Dd); rstride = Dd; }

    // ---- X A-fragments for this wave's M-tile (loaded once, bf16) ----
    v8s xfrag[2];
#pragma unroll
    for (int ks = 0; ks < 2; ++ks) {
        const float* xp = x + base + (w*16 + l15)*rstride + ks*32 + quad*8;
        float4 a = *reinterpret_cast<const float4*>(xp);
        float4 b = *reinterpret_cast<const float4*>(xp + 4);
        v8s f;
        f[0]=(short)f2b(a.x); f[1]=(short)f2b(a.y); f[2]=(short)f2b(a.z); f[3]=(short)f2b(a.w);
        f[4]=(short)f2b(b.x); f[5]=(short)f2b(b.y); f[6]=(short)f2b(b.z); f[7]=(short)f2b(b.w);
        xfrag[ks] = f;
    }

    v4f outAcc[4];
#pragma unroll
    for (int i = 0; i < 4; ++i) outAcc[i] = (v4f){0.f,0.f,0.f,0.f};

    const float scale = 0.17677669529663687f;   // 1/sqrt(32)
    const v4f vzero = (v4f){0.f,0.f,0.f,0.f};

#pragma unroll 1
    for (int h = 0; h < Hh; ++h) {
        // ================= Q projection =================
        __syncthreads();                               // WlT free (prior head done)
        for (int idx = tid; idx < 2048; idx += NT) {   // stage Wq^T: [ch][d]
            int ch = idx & 31, d = idx >> 5;
            sm[o_wlt + ch*72 + d] = f2b(wq[d*128 + h*32 + ch]);
        }
        __syncthreads();
#pragma unroll
        for (int nt = 0; nt < 2; ++nt) {
            v4f acc = vzero;
#pragma unroll
            for (int ks = 0; ks < 2; ++ks) {
                v8s wf = *reinterpret_cast<const v8s*>(&sm[o_wlt + (nt*16+l15)*72 + ks*32 + quad*8]);
                acc = MFMA(xfrag[ks], wf, acc);
            }
            float bias = bq[h*32 + nt*16 + l15];
#pragma unroll
            for (int r = 0; r < 4; ++r)
                sm[o_ql + (w*16 + quad*4 + r)*32 + nt*16 + l15] = f2b((acc[r] + bias) * scale);
        }
        // ================= K projection =================
        __syncthreads();                               // all Q-mfma reads of WlT done
        for (int idx = tid; idx < 2048; idx += NT) {
            int ch = idx & 31, d = idx >> 5;
            sm[o_wlt + ch*72 + d] = f2b(wk[d*128 + h*32 + ch]);
        }
        __syncthreads();
#pragma unroll
        for (int nt = 0; nt < 2; ++nt) {
            v4f acc = vzero;
#pragma unroll
            for (int ks = 0; ks < 2; ++ks) {
                v8s wf = *reinterpret_cast<const v8s*>(&sm[o_wlt + (nt*16+l15)*72 + ks*32 + quad*8]);
                acc = MFMA(xfrag[ks], wf, acc);
            }
            float bias = bk[h*32 + nt*16 + l15];
#pragma unroll
            for (int r = 0; r < 4; ++r)
                sm[o_kl + (w*16 + quad*4 + r)*32 + nt*16 + l15] = f2b(acc[r] + bias);
        }
        // ================= V projection =================
        __syncthreads();
        for (int idx = tid; idx < 2048; idx += NT) {
            int ch = idx & 31, d = idx >> 5;
            sm[o_wlt + ch*72 + d] = f2b(wv[d*128 + h*32 + ch]);
        }
        __syncthreads();
#pragma unroll
        for (int nt = 0; nt < 2; ++nt) {
            v4f acc = vzero;
#pragma unroll
            for (int ks = 0; ks < 2; ++ks) {
                v8s wf = *reinterpret_cast<const v8s*>(&sm[o_wlt + (nt*16+l15)*72 + ks*32 + quad*8]);
                acc = MFMA(xfrag[ks], wf, acc);
            }
            float bias = bv[h*32 + nt*16 + l15];
            // transpose-scatter into V^T: 4 consecutive rows -> one b64 pack
            u32 lo = (u32)f2b(acc[0]+bias) | ((u32)f2b(acc[1]+bias) << 16);
            u32 hi = (u32)f2b(acc[2]+bias) | ((u32)f2b(acc[3]+bias) << 16);
            int ch = nt*16 + l15;
            *reinterpret_cast<uint2*>(&sm[o_vt + ch*NRp + w*16 + quad*4]) = make_uint2(lo, hi);
        }
        // stage Wo^T for this head (independent buffer; visible after next barrier)
        for (int idx = tid; idx < 2048; idx += NT) {
            int d = idx & 63, k2 = idx >> 6;
            sm[o_wot + d*40 + k2] = f2b(wo[h*2048 + k2*64 + d]);
        }
        __syncthreads();   // Ql, Kl, Vt, WoT all visible
        // ================= S = Q K^T (K=32: one k-step) =================
        v8s qf = *reinterpret_cast<const v8s*>(&sm[o_ql + (w*16 + l15)*32 + quad*8]);
        v4f S[W];
#pragma unroll
        for (int ct = 0; ct < W; ++ct) {
            v8s kf = *reinterpret_cast<const v8s*>(&sm[o_kl + (ct*16 + l15)*32 + quad*8]);
            S[ct] = MFMA(qf, kf, vzero);
        }
        // ================= softmax (exact, rows quad*4+r) =================
        float mrow[4], rl[4];
#pragma unroll
        for (int r = 0; r < 4; ++r) {
            float mm = S[0][r];
#pragma unroll
            for (int ct = 1; ct < W; ++ct) mm = fmaxf(mm, S[ct][r]);
#pragma unroll
            for (int msk = 1; msk < 16; msk <<= 1) mm = fmaxf(mm, __shfl_xor(mm, msk, 16));
            mrow[r] = mm;
        }
#pragma unroll
        for (int r = 0; r < 4; ++r) {
            float ss = 0.f;
#pragma unroll
            for (int ct = 0; ct < W; ++ct) { float p = __expf(S[ct][r] - mrow[r]); S[ct][r] = p; ss += p; }
#pragma unroll
            for (int msk = 1; msk < 16; msk <<= 1) ss += __shfl_xor(ss, msk, 16);
            rl[r] = 1.f / ss;
        }
        // write normalized P (bf16) into A-container
#pragma unroll
        for (int ct = 0; ct < W; ++ct)
#pragma unroll
            for (int r = 0; r < 4; ++r)
                sm[o_pl + (w*16 + quad*4 + r)*NRp + ct*16 + l15] = f2b(S[ct][r] * rl[r]);
        __syncthreads();
        // ================= O = P V =================
        v4f Oacc[2] = { vzero, vzero };
#pragma unroll
        for (int ks = 0; ks < NR/32; ++ks) {
            v8s pf = *reinterpret_cast<const v8s*>(&sm[o_pl + (w*16 + l15)*NRp + ks*32 + quad*8]);
#pragma unroll
            for (int nt = 0; nt < 2; ++nt) {
                v8s vf = *reinterpret_cast<const v8s*>(&sm[o_vt + (nt*16 + l15)*NRp + ks*32 + quad*8]);
                Oacc[nt] = MFMA(pf, vf, Oacc[nt]);
            }
        }
#pragma unroll
        for (int nt = 0; nt < 2; ++nt)
#pragma unroll
            for (int r = 0; r < 4; ++r)
                sm[o_ot + (w*16 + quad*4 + r)*32 + nt*16 + l15] = f2b(Oacc[nt][r]);
        __syncthreads();
        // ================= out += O Wo_h =================
        v8s of = *reinterpret_cast<const v8s*>(&sm[o_ot + (w*16 + l15)*32 + quad*8]);
#pragma unroll
        for (int nt = 0; nt < 4; ++nt) {
            v8s wf = *reinterpret_cast<const v8s*>(&sm[o_wot + (nt*16 + l15)*40 + quad*8]);
            outAcc[nt] = MFMA(of, wf, outAcc[nt]);
        }
    }

    // ================= epilogue (fp32) =================
#pragma unroll
    for (int nt = 0; nt < 4; ++nt) {
        int d = nt*16 + l15;
        float bias = bo[d];
#pragma unroll
        for (int r = 0; r < 4; ++r) {
            int row = w*16 + quad*4 + r;
            float* p = out + base + row*rstride + d;
            float v = outAcc[nt][r] + bias;
            if (MODE == 1) v += *p;
            *p = v;
        }
    }
}

extern "C" void kernel_launch(void* const* d_in, const int* in_sizes, int n_in,
                              void* d_out, int out_size, void* d_ws, size_t ws_size,
                              hipStream_t stream) {
    const float* x   = (const float*)d_in[0];
    const float* tqw = (const float*)d_in[1];  const float* tqb = (const float*)d_in[2];
    const float* tkw = (const float*)d_in[3];  const float* tkb = (const float*)d_in[4];
    const float* tvw = (const float*)d_in[5];  const float* tvb = (const float*)d_in[6];
    const float* fqw = (const float*)d_in[7];  const float* fqb = (const float*)d_in[8];
    const float* fkw = (const float*)d_in[9];  const float* fkb = (const float*)d_in[10];
    const float* fvw = (const float*)d_in[11]; const float* fvb = (const float*)d_in[12];
    const float* tow = (const float*)d_in[13]; const float* tob = (const float*)d_in[14];
    const float* fow = (const float*)d_in[15]; const float* fob = (const float*)d_in[16];
    float* out = (float*)d_out;

    // temporal: block per (b,f), 4 waves, writes fp32 partial
    hipLaunchKernelGGL((axial_mfma<64,0>), dim3(Bb*Ff), dim3(256), 0, stream,
                       x, tqw, tqb, tkw, tkb, tvw, tvb, tow, tob, out);
    // feature: block per (b,t), 8 waves, reads partial, adds, writes final
    hipLaunchKernelGGL((axial_mfma<128,1>), dim3(Bb*Tt), dim3(512), 0, stream,
                       x, fqw, fqb, fkw, fkb, fvw, fvb, fow, fob, out);
}

// Round 5
// 390.785 us; speedup vs baseline: 4.1952x; 1.2516x over previous
//
#include <hip/hip_runtime.h>

typedef unsigned short u16;
typedef unsigned int   u32;
typedef short v8s __attribute__((ext_vector_type(8)));   // 8 bf16 (A/B frag, 4 VGPR)
typedef float v4f __attribute__((ext_vector_type(4)));   // 4 fp32 (C/D frag)

#define DEV __device__ __forceinline__
#define MFMA(a,b,c) __builtin_amdgcn_mfma_f32_16x16x32_bf16((a),(b),(c),0,0,0)

constexpr int Bb = 32, Tt = 64, Ff = 128, Dd = 64, Hh = 4, Kk = 32;

DEV u16 f2b(float f) {
    u32 u = __float_as_uint(f);
    return (u16)((u + 0x7fffu + ((u >> 16) & 1u)) >> 16);   // RNE
}

// ---- prep: convert all weights to bf16 B-containers in ws (128 KB) ----
// ws layout (u16):
//   [0, 49152)      : 6 proj  x [h][ch=32][d=64]   (tq,tk,tv,fq,fk,fv)
//   [49152, 65536)  : 2 woT   x [h][d=64][k=32]    (to, fo)
__global__ __launch_bounds__(256)
void prep_weights(const float* __restrict__ tq, const float* __restrict__ tk,
                  const float* __restrict__ tv, const float* __restrict__ fq,
                  const float* __restrict__ fk, const float* __restrict__ fv,
                  const float* __restrict__ to_, const float* __restrict__ fo,
                  u16* __restrict__ ws)
{
    int idx = blockIdx.x * 256 + threadIdx.x;          // 0..65535
    if (idx < 49152) {
        int p = idx >> 13, rem = idx & 8191;           // [h][ch][d]
        int h = rem >> 11, ch = (rem >> 6) & 31, d = rem & 63;
        const float* w = (p==0)?tq:(p==1)?tk:(p==2)?tv:(p==3)?fq:(p==4)?fk:fv;
        ws[idx] = f2b(w[d*128 + h*32 + ch]);           // w[d][h][ch]
    } else {
        int i2 = idx - 49152;
        int path = i2 >> 13, rem = i2 & 8191;          // [h][d][k]
        int h = rem >> 11, d = (rem >> 5) & 63, k2 = rem & 31;
        const float* w = path ? fo : to_;
        ws[idx] = f2b(w[h*2048 + k2*64 + d]);          // wo[h][k][d]
    }
}

// Fragment layout rules (HW-verified, learn_hip m89/m120):
//   A-frag: lane holds A[m][k], m=lane&15, k=quad*8+j  -> container row-major [m][k]
//   B-frag: lane holds B[k][n], n=lane&15, k=quad*8+j  -> container [n][k]
//   C/D:    lane holds D[row][col], col=lane&15, row=quad*4+r
// MODE 0: temporal (NR=64 rows=T, block per (b,f)), writes fp32 partial.
// MODE 1: feature (NR=128 rows=F, block per (b,t)), read-add-write final.
template<int NR, int MODE>
__global__ __launch_bounds__(NR*4)
void axial_mfma(const float* __restrict__ x, const u16* __restrict__ wsw,
                const float* __restrict__ bq, const float* __restrict__ bk,
                const float* __restrict__ bv, const float* __restrict__ bo,
                float* __restrict__ out)
{
    constexpr int W   = NR / 16;      // waves per block
    constexpr int NT  = W * 64;
    constexpr int NRp = NR + 8;       // padded pitch, keeps 16B align (NRp*2 % 16 == 0)
    constexpr int o_ql = 0;                  // Q, later reused as O  [NR][32]
    constexpr int o_kl = o_ql + NR * 32;     // K    [NR][32]
    constexpr int o_vt = o_kl + NR * 32;     // V^T  [32][NRp]
    constexpr int o_pl = o_vt + 32 * NRp;    // P    [NR][NRp]
    constexpr int SMEM = o_pl + NR * NRp;
    __shared__ alignas(16) u16 sm[SMEM];
    (void)NT;

    const int tid  = threadIdx.x;
    const int w    = tid >> 6;
    const int lane = tid & 63;
    const int quad = lane >> 4;
    const int l15  = lane & 15;
    const int bid  = blockIdx.x;

    int base, rstride;
    if (MODE == 0) { int b = bid >> 7, f = bid & 127; base = b*(Tt*Ff*Dd) + f*Dd; rstride = Ff*Dd; }
    else           { base = bid * (Ff*Dd); rstride = Dd; }

    // weight container bases (bf16, prepared by prep_weights)
    constexpr int PB = (MODE == 0) ? 0 : 3;
    const u16* wql = wsw + (PB+0)*8192;
    const u16* wkl = wsw + (PB+1)*8192;
    const u16* wvl = wsw + (PB+2)*8192;
    const u16* wol = wsw + 49152 + MODE*8192;

    // ---- X A-fragments for this wave's M-tile (loaded once, bf16) ----
    v8s xfrag[2];
#pragma unroll
    for (int ks = 0; ks < 2; ++ks) {
        const float* xp = x + base + (w*16 + l15)*rstride + ks*32 + quad*8;
        float4 a = *reinterpret_cast<const float4*>(xp);
        float4 b = *reinterpret_cast<const float4*>(xp + 4);
        v8s f;
        f[0]=(short)f2b(a.x); f[1]=(short)f2b(a.y); f[2]=(short)f2b(a.z); f[3]=(short)f2b(a.w);
        f[4]=(short)f2b(b.x); f[5]=(short)f2b(b.y); f[6]=(short)f2b(b.z); f[7]=(short)f2b(b.w);
        xfrag[ks] = f;
    }

    v4f outAcc[4];
#pragma unroll
    for (int i = 0; i < 4; ++i) outAcc[i] = (v4f){0.f,0.f,0.f,0.f};

    const float scale = 0.17677669529663687f;   // 1/sqrt(32)
    const v4f vzero = (v4f){0.f,0.f,0.f,0.f};

#pragma unroll 1
    for (int h = 0; h < Hh; ++h) {
        // barrier 1: previous head's cross-wave K/V^T reads done before overwrite
        __syncthreads();

        // ================= Q projection (weights direct from global) ========
        {
            const u16* wb = wql + h*2048;
#pragma unroll
            for (int nt = 0; nt < 2; ++nt) {
                v4f acc = vzero;
#pragma unroll
                for (int ks = 0; ks < 2; ++ks) {
                    v8s wf = *reinterpret_cast<const v8s*>(wb + (nt*16+l15)*64 + ks*32 + quad*8);
                    acc = MFMA(xfrag[ks], wf, acc);
                }
                float bias = bq[h*32 + nt*16 + l15];
#pragma unroll
                for (int r = 0; r < 4; ++r)
                    sm[o_ql + (w*16 + quad*4 + r)*32 + nt*16 + l15] = f2b((acc[r] + bias) * scale);
            }
        }
        // ================= K projection =====================================
        {
            const u16* wb = wkl + h*2048;
#pragma unroll
            for (int nt = 0; nt < 2; ++nt) {
                v4f acc = vzero;
#pragma unroll
                for (int ks = 0; ks < 2; ++ks) {
                    v8s wf = *reinterpret_cast<const v8s*>(wb + (nt*16+l15)*64 + ks*32 + quad*8);
                    acc = MFMA(xfrag[ks], wf, acc);
                }
                float bias = bk[h*32 + nt*16 + l15];
#pragma unroll
                for (int r = 0; r < 4; ++r)
                    sm[o_kl + (w*16 + quad*4 + r)*32 + nt*16 + l15] = f2b(acc[r] + bias);
            }
        }
        // ================= V projection (transposed b64 pack) ===============
        {
            const u16* wb = wvl + h*2048;
#pragma unroll
            for (int nt = 0; nt < 2; ++nt) {
                v4f acc = vzero;
#pragma unroll
                for (int ks = 0; ks < 2; ++ks) {
                    v8s wf = *reinterpret_cast<const v8s*>(wb + (nt*16+l15)*64 + ks*32 + quad*8);
                    acc = MFMA(xfrag[ks], wf, acc);
                }
                float bias = bv[h*32 + nt*16 + l15];
                u32 lo = (u32)f2b(acc[0]+bias) | ((u32)f2b(acc[1]+bias) << 16);
                u32 hi = (u32)f2b(acc[2]+bias) | ((u32)f2b(acc[3]+bias) << 16);
                int ch = nt*16 + l15;
                *reinterpret_cast<uint2*>(&sm[o_vt + ch*NRp + w*16 + quad*4]) = make_uint2(lo, hi);
            }
        }
        // barrier 2: K and V^T (cross-wave operands) visible
        __syncthreads();

        // ================= S = Q K^T (K=32: one k-step) =====================
        v8s qf = *reinterpret_cast<const v8s*>(&sm[o_ql + (w*16 + l15)*32 + quad*8]);  // own-wave rows
        v4f S[W];
#pragma unroll
        for (int ct = 0; ct < W; ++ct) {
            v8s kf = *reinterpret_cast<const v8s*>(&sm[o_kl + (ct*16 + l15)*32 + quad*8]);
            S[ct] = MFMA(qf, kf, vzero);
        }
        // ================= softmax (exact, rows quad*4+r) ===================
        float mrow[4], rl[4];
#pragma unroll
        for (int r = 0; r < 4; ++r) {
            float mm = S[0][r];
#pragma unroll
            for (int ct = 1; ct < W; ++ct) mm = fmaxf(mm, S[ct][r]);
#pragma unroll
            for (int msk = 1; msk < 16; msk <<= 1) mm = fmaxf(mm, __shfl_xor(mm, msk, 16));
            mrow[r] = mm;
        }
#pragma unroll
        for (int r = 0; r < 4; ++r) {
            float ss = 0.f;
#pragma unroll
            for (int ct = 0; ct < W; ++ct) { float p = __expf(S[ct][r] - mrow[r]); S[ct][r] = p; ss += p; }
#pragma unroll
            for (int msk = 1; msk < 16; msk <<= 1) ss += __shfl_xor(ss, msk, 16);
            rl[r] = 1.f / ss;
        }
        // write normalized P into own-wave rows (wave-local RAW, no barrier)
#pragma unroll
        for (int ct = 0; ct < W; ++ct)
#pragma unroll
            for (int r = 0; r < 4; ++r)
                sm[o_pl + (w*16 + quad*4 + r)*NRp + ct*16 + l15] = f2b(S[ct][r] * rl[r]);

        // ================= O = P V (pf own-wave, vf cross-wave) =============
        v4f Oacc[2] = { vzero, vzero };
#pragma unroll
        for (int ks = 0; ks < NR/32; ++ks) {
            v8s pf = *reinterpret_cast<const v8s*>(&sm[o_pl + (w*16 + l15)*NRp + ks*32 + quad*8]);
#pragma unroll
            for (int nt = 0; nt < 2; ++nt) {
                v8s vf = *reinterpret_cast<const v8s*>(&sm[o_vt + (nt*16 + l15)*NRp + ks*32 + quad*8]);
                Oacc[nt] = MFMA(pf, vf, Oacc[nt]);
            }
        }
        // O into the Q container (own-wave rows; qf already consumed)
#pragma unroll
        for (int nt = 0; nt < 2; ++nt)
#pragma unroll
            for (int r = 0; r < 4; ++r)
                sm[o_ql + (w*16 + quad*4 + r)*32 + nt*16 + l15] = f2b(Oacc[nt][r]);

        // ================= out += O Wo_h (Wo frags direct from global) ======
        v8s of = *reinterpret_cast<const v8s*>(&sm[o_ql + (w*16 + l15)*32 + quad*8]);  // own-wave
        {
            const u16* wb = wol + h*2048;
#pragma unroll
            for (int nt = 0; nt < 4; ++nt) {
                v8s wf = *reinterpret_cast<const v8s*>(wb + (nt*16 + l15)*32 + quad*8);
                outAcc[nt] = MFMA(of, wf, outAcc[nt]);
            }
        }
    }

    // ================= epilogue (fp32) =================
#pragma unroll
    for (int nt = 0; nt < 4; ++nt) {
        int d = nt*16 + l15;
        float bias = bo[d];
#pragma unroll
        for (int r = 0; r < 4; ++r) {
            int row = w*16 + quad*4 + r;
            float* p = out + base + row*rstride + d;
            float v = outAcc[nt][r] + bias;
            if (MODE == 1) v += *p;
            *p = v;
        }
    }
}

extern "C" void kernel_launch(void* const* d_in, const int* in_sizes, int n_in,
                              void* d_out, int out_size, void* d_ws, size_t ws_size,
                              hipStream_t stream) {
    const float* x   = (const float*)d_in[0];
    const float* tqw = (const float*)d_in[1];  const float* tqb = (const float*)d_in[2];
    const float* tkw = (const float*)d_in[3];  const float* tkb = (const float*)d_in[4];
    const float* tvw = (const float*)d_in[5];  const float* tvb = (const float*)d_in[6];
    const float* fqw = (const float*)d_in[7];  const float* fqb = (const float*)d_in[8];
    const float* fkw = (const float*)d_in[9];  const float* fkb = (const float*)d_in[10];
    const float* fvw = (const float*)d_in[11]; const float* fvb = (const float*)d_in[12];
    const float* tow = (const float*)d_in[13]; const float* tob = (const float*)d_in[14];
    const float* fow = (const float*)d_in[15]; const float* fob = (const float*)d_in[16];
    float* out = (float*)d_out;
    u16* ws = (u16*)d_ws;   // needs 128 KB

    hipLaunchKernelGGL(prep_weights, dim3(256), dim3(256), 0, stream,
                       tqw, tkw, tvw, fqw, fkw, fvw, tow, fow, ws);
    // temporal: block per (b,f), 4 waves, writes fp32 partial
    hipLaunchKernelGGL((axial_mfma<64,0>), dim3(Bb*Ff), dim3(256), 0, stream,
                       x, ws, tqb, tkb, tvb, tob, out);
    // feature: block per (b,t), 8 waves, reads partial, adds, writes final
    hipLaunchKernelGGL((axial_mfma<128,1>), dim3(Bb*Tt), dim3(512), 0, stream,
                       x, ws, fqb, fkb, fvb, fob, out);
}

// Round 6
// 380.957 us; speedup vs baseline: 4.3034x; 1.0258x over previous
//
#include <hip/hip_runtime.h>

typedef unsigned short u16;
typedef unsigned int   u32;
typedef short v8s __attribute__((ext_vector_type(8)));   // 8 bf16 (A/B frag, 4 VGPR)
typedef float v4f __attribute__((ext_vector_type(4)));   // 4 fp32 (C/D frag)

#define DEV __device__ __forceinline__
#define MFMA(a,b,c) __builtin_amdgcn_mfma_f32_16x16x32_bf16((a),(b),(c),0,0,0)

constexpr int Bb = 32, Tt = 64, Ff = 128, Dd = 64, Hh = 4, Kk = 32;

DEV u16 f2b(float f) {                       // RNE (prep kernel only)
    u32 u = __float_as_uint(f);
    return (u16)((u + 0x7fffu + ((u >> 16) & 1u)) >> 16);
}
DEV u32 pk2(float a, float b) {              // round-half-up pair pack (2 bf16 in u32)
    u32 x = __float_as_uint(a) + 0x8000u;
    u32 y = __float_as_uint(b) + 0x8000u;
    return (x >> 16) | (y & 0xffff0000u);
}

// ---- prep: convert all weights to bf16 containers in ws (128 KB) ----
// ws layout (u16):
//   [0, 49152)      : 6 proj  x [h][ch=32][d=64]   (tq,tk,tv,fq,fk,fv)
//   [49152, 65536)  : 2 woT   x [h][d=64][k=32]    (to, fo)
__global__ __launch_bounds__(256)
void prep_weights(const float* __restrict__ tq, const float* __restrict__ tk,
                  const float* __restrict__ tv, const float* __restrict__ fq,
                  const float* __restrict__ fk, const float* __restrict__ fv,
                  const float* __restrict__ to_, const float* __restrict__ fo,
                  u16* __restrict__ ws)
{
    int idx = blockIdx.x * 256 + threadIdx.x;          // 0..65535
    if (idx < 49152) {
        int p = idx >> 13, rem = idx & 8191;           // [h][ch][d]
        int h = rem >> 11, ch = (rem >> 6) & 31, d = rem & 63;
        const float* w = (p==0)?tq:(p==1)?tk:(p==2)?tv:(p==3)?fq:(p==4)?fk:fv;
        ws[idx] = f2b(w[d*128 + h*32 + ch]);           // w[d][h][ch]
    } else {
        int i2 = idx - 49152;
        int path = i2 >> 13, rem = i2 & 8191;          // [h][d][k]
        int h = rem >> 11, d = (rem >> 5) & 63, k2 = rem & 31;
        const float* w = path ? fo : to_;
        ws[idx] = f2b(w[h*2048 + k2*64 + d]);          // wo[h][k][d]
    }
}

// Fragment facts (HW-verified, learn_hip m89/m120):
//   A-frag: lane = A[m][k], m=lane&15, k=quad*8+j  (container row-major [m][k])
//   B-frag: lane = B[k][n], n=lane&15, k=quad*8+j  (container [n][k])
//   C/D:    lane = D[row][col], col=lane&15, row=quad*4+r
//   MFMA(A,B) -> D[m][n] = sum_k A[m][k]*B[n][k]; swapping operands transposes D.
// MODE 0: temporal (NR=64 rows=T, block per (b,f)), writes fp32 partial.
// MODE 1: feature (NR=128 rows=F, block per (b,t)), read-add-write final.
template<int NR, int MODE>
__global__ __launch_bounds__(NR*4)
void axial_mfma(const float* __restrict__ x, const u16* __restrict__ wsw,
                const float* __restrict__ bq, const float* __restrict__ bk,
                const float* __restrict__ bv, const float* __restrict__ bo,
                float* __restrict__ out)
{
    constexpr int W   = NR / 16;      // waves per block
    constexpr int QP  = 40;           // Q/K/O row pitch (80B: 16B-aligned, 2-way-free banks)
    constexpr int NRp = NR + 8;       // V^T/P pitch (16B-aligned)
    constexpr int o_q  = 0;                   // Q, reused as O  [NR][QP]   (own-wave rows only)
    constexpr int o_k  = o_q + NR * QP;       // K    [NR][QP]
    constexpr int o_vt = o_k + NR * QP;       // V^T  [32][NRp]
    constexpr int o_p  = o_vt + 32 * NRp;     // P    [NR][NRp]
    constexpr int SMEM = o_p + NR * NRp;      // feature: 64000 B, temporal: 24064 B
    __shared__ alignas(16) u16 sm[SMEM];

    const int tid  = threadIdx.x;
    const int w    = tid >> 6;
    const int lane = tid & 63;
    const int quad = lane >> 4;
    const int l15  = lane & 15;
    const int bid  = blockIdx.x;

    int base, rstride;
    if (MODE == 0) { int b = bid >> 7, f = bid & 127; base = b*(Tt*Ff*Dd) + f*Dd; rstride = Ff*Dd; }
    else           { base = bid * (Ff*Dd); rstride = Dd; }

    constexpr int PB = (MODE == 0) ? 0 : 3;
    const u16* wql = wsw + (PB+0)*8192;
    const u16* wkl = wsw + (PB+1)*8192;
    const u16* wvl = wsw + (PB+2)*8192;
    const u16* wol = wsw + 49152 + MODE*8192;

    // ---- X fragments (dual-use as A or B; same lane mapping), row w*16+l15 ----
    v8s xfrag[2];
#pragma unroll
    for (int ks = 0; ks < 2; ++ks) {
        const float* xp = x + base + (w*16 + l15)*rstride + ks*32 + quad*8;
        float4 a = *reinterpret_cast<const float4*>(xp);
        float4 b = *reinterpret_cast<const float4*>(xp + 4);
        v8s f;
        u32* fu = reinterpret_cast<u32*>(&f);
        fu[0] = pk2(a.x, a.y); fu[1] = pk2(a.z, a.w);
        fu[2] = pk2(b.x, b.y); fu[3] = pk2(b.z, b.w);
        xfrag[ks] = f;
    }

    v4f outAcc[4];
#pragma unroll
    for (int i = 0; i < 4; ++i) outAcc[i] = (v4f){0.f,0.f,0.f,0.f};

    const float scale = 0.17677669529663687f;   // 1/sqrt(32)
    const v4f vzero = (v4f){0.f,0.f,0.f,0.f};

#pragma unroll 1
    for (int h = 0; h < Hh; ++h) {
        // barrier 1: prev head's cross-wave K/V^T reads complete before overwrite
        __syncthreads();

        // ===== Q^T proj: MFMA(Wq^T, X) -> D[ch][qrow]; lane = 4 consecutive ch =====
        {
            const u16* wb = wql + h*2048;
#pragma unroll
            for (int nt = 0; nt < 2; ++nt) {
                v4f acc = vzero;
#pragma unroll
                for (int ks = 0; ks < 2; ++ks) {
                    v8s wf = *reinterpret_cast<const v8s*>(wb + (nt*16+l15)*64 + ks*32 + quad*8);
                    acc = MFMA(wf, xfrag[ks], acc);
                }
                float4 b4 = *reinterpret_cast<const float4*>(bq + h*32 + nt*16 + quad*4);
                u32 lo = pk2((acc[0]+b4.x)*scale, (acc[1]+b4.y)*scale);
                u32 hi = pk2((acc[2]+b4.z)*scale, (acc[3]+b4.w)*scale);
                *reinterpret_cast<uint2*>(&sm[o_q + (w*16+l15)*QP + nt*16 + quad*4]) = make_uint2(lo, hi);
            }
        }
        // ===== K^T proj =====
        {
            const u16* wb = wkl + h*2048;
#pragma unroll
            for (int nt = 0; nt < 2; ++nt) {
                v4f acc = vzero;
#pragma unroll
                for (int ks = 0; ks < 2; ++ks) {
                    v8s wf = *reinterpret_cast<const v8s*>(wb + (nt*16+l15)*64 + ks*32 + quad*8);
                    acc = MFMA(wf, xfrag[ks], acc);
                }
                float4 b4 = *reinterpret_cast<const float4*>(bk + h*32 + nt*16 + quad*4);
                u32 lo = pk2(acc[0]+b4.x, acc[1]+b4.y);
                u32 hi = pk2(acc[2]+b4.z, acc[3]+b4.w);
                *reinterpret_cast<uint2*>(&sm[o_k + (w*16+l15)*QP + nt*16 + quad*4]) = make_uint2(lo, hi);
            }
        }
        // ===== V proj (non-transposed): D[krow][ch], lane = 4 consecutive krows =====
        {
            const u16* wb = wvl + h*2048;
#pragma unroll
            for (int nt = 0; nt < 2; ++nt) {
                v4f acc = vzero;
#pragma unroll
                for (int ks = 0; ks < 2; ++ks) {
                    v8s wf = *reinterpret_cast<const v8s*>(wb + (nt*16+l15)*64 + ks*32 + quad*8);
                    acc = MFMA(xfrag[ks], wf, acc);
                }
                float bias = bv[h*32 + nt*16 + l15];
                u32 lo = pk2(acc[0]+bias, acc[1]+bias);
                u32 hi = pk2(acc[2]+bias, acc[3]+bias);
                int ch = nt*16 + l15;
                *reinterpret_cast<uint2*>(&sm[o_vt + ch*NRp + w*16 + quad*4]) = make_uint2(lo, hi);
            }
        }
        // barrier 2: K, V^T (cross-wave operands) visible
        __syncthreads();

        // ===== S^T = MFMA(K, Q) -> D[krow][qrow]; lane: qrow=l15, 4 consec krows =====
        v8s qf = *reinterpret_cast<const v8s*>(&sm[o_q + (w*16+l15)*QP + quad*8]);   // own-wave
        v4f S[W];
#pragma unroll
        for (int ct = 0; ct < W; ++ct) {
            v8s kf = *reinterpret_cast<const v8s*>(&sm[o_k + (ct*16+l15)*QP + quad*8]);
            S[ct] = MFMA(kf, qf, vzero);
        }
        // ===== softmax over keys (per-lane row; reduce in-reg then xor 16,32) =====
        float mm = S[0][0];
#pragma unroll
        for (int ct = 0; ct < W; ++ct)
#pragma unroll
            for (int r = 0; r < 4; ++r) mm = fmaxf(mm, S[ct][r]);
        mm = fmaxf(mm, __shfl_xor(mm, 16));
        mm = fmaxf(mm, __shfl_xor(mm, 32));
        float ss = 0.f;
#pragma unroll
        for (int ct = 0; ct < W; ++ct)
#pragma unroll
            for (int r = 0; r < 4; ++r) { float p = __expf(S[ct][r] - mm); S[ct][r] = p; ss += p; }
        ss += __shfl_xor(ss, 16);
        ss += __shfl_xor(ss, 32);
        float rl = 1.f / ss;
        // P[qrow][krow], packed b64 per tile (own-wave row)
#pragma unroll
        for (int ct = 0; ct < W; ++ct) {
            u32 lo = pk2(S[ct][0]*rl, S[ct][1]*rl);
            u32 hi = pk2(S[ct][2]*rl, S[ct][3]*rl);
            *reinterpret_cast<uint2*>(&sm[o_p + (w*16+l15)*NRp + ct*16 + quad*4]) = make_uint2(lo, hi);
        }

        // ===== O^T = MFMA(V^T, P) -> D[ch][qrow]; lane = 4 consec ch =====
        v4f Oacc[2] = { vzero, vzero };
#pragma unroll
        for (int ks = 0; ks < NR/32; ++ks) {
            v8s pf = *reinterpret_cast<const v8s*>(&sm[o_p + (w*16+l15)*NRp + ks*32 + quad*8]);  // own-wave
#pragma unroll
            for (int nt = 0; nt < 2; ++nt) {
                v8s vf = *reinterpret_cast<const v8s*>(&sm[o_vt + (nt*16+l15)*NRp + ks*32 + quad*8]);
                Oacc[nt] = MFMA(vf, pf, Oacc[nt]);
            }
        }
        // O into Q container (own-wave row; qf already consumed)
#pragma unroll
        for (int nt = 0; nt < 2; ++nt) {
            u32 lo = pk2(Oacc[nt][0], Oacc[nt][1]);
            u32 hi = pk2(Oacc[nt][2], Oacc[nt][3]);
            *reinterpret_cast<uint2*>(&sm[o_q + (w*16+l15)*QP + nt*16 + quad*4]) = make_uint2(lo, hi);
        }

        // ===== out^T += MFMA(Wo^T, O) -> D[d][qrow]; lane = 4 consec d =====
        v8s of = *reinterpret_cast<const v8s*>(&sm[o_q + (w*16+l15)*QP + quad*8]);   // own-wave
        {
            const u16* wb = wol + h*2048;
#pragma unroll
            for (int nt = 0; nt < 4; ++nt) {
                v8s wf = *reinterpret_cast<const v8s*>(wb + (nt*16+l15)*32 + quad*8);
                outAcc[nt] = MFMA(wf, of, outAcc[nt]);
            }
        }
    }

    // ===== epilogue: lane owns row w*16+l15, d = nt*16+quad*4 .. +3 (float4) =====
    float* orow = out + base + (w*16 + l15)*rstride;
#pragma unroll
    for (int nt = 0; nt < 4; ++nt) {
        int d0 = nt*16 + quad*4;
        float4 b4 = *reinterpret_cast<const float4*>(bo + d0);
        float4 v = make_float4(outAcc[nt][0]+b4.x, outAcc[nt][1]+b4.y,
                               outAcc[nt][2]+b4.z, outAcc[nt][3]+b4.w);
        if (MODE == 1) {
            float4 p = *reinterpret_cast<const float4*>(orow + d0);
            v.x += p.x; v.y += p.y; v.z += p.z; v.w += p.w;
        }
        *reinterpret_cast<float4*>(orow + d0) = v;
    }
}

extern "C" void kernel_launch(void* const* d_in, const int* in_sizes, int n_in,
                              void* d_out, int out_size, void* d_ws, size_t ws_size,
                              hipStream_t stream) {
    const float* x   = (const float*)d_in[0];
    const float* tqw = (const float*)d_in[1];  const float* tqb = (const float*)d_in[2];
    const float* tkw = (const float*)d_in[3];  const float* tkb = (const float*)d_in[4];
    const float* tvw = (const float*)d_in[5];  const float* tvb = (const float*)d_in[6];
    const float* fqw = (const float*)d_in[7];  const float* fqb = (const float*)d_in[8];
    const float* fkw = (const float*)d_in[9];  const float* fkb = (const float*)d_in[10];
    const float* fvw = (const float*)d_in[11]; const float* fvb = (const float*)d_in[12];
    const float* tow = (const float*)d_in[13]; const float* tob = (const float*)d_in[14];
    const float* fow = (const float*)d_in[15]; const float* fob = (const float*)d_in[16];
    float* out = (float*)d_out;
    u16* ws = (u16*)d_ws;   // 128 KB

    hipLaunchKernelGGL(prep_weights, dim3(256), dim3(256), 0, stream,
                       tqw, tkw, tvw, fqw, fkw, fvw, tow, fow, ws);
    hipLaunchKernelGGL((axial_mfma<64,0>), dim3(Bb*Ff), dim3(256), 0, stream,
                       x, ws, tqb, tkb, tvb, tob, out);
    hipLaunchKernelGGL((axial_mfma<128,1>), dim3(Bb*Tt), dim3(512), 0, stream,
                       x, ws, fqb, fkb, fvb, fob, out);
}